// Round 1
// baseline (60.812 us; speedup 1.0000x reference)
//
#include <hip/hip_runtime.h>

#define SEQ 4096
#define DIM 1024
#define NB  8
#define NP  8
#define M   64   // NB*NP

// Kernel 1: per batch b — scan mask for positions of first 9 ones, then
// compute the 8 bucket means directly (buckets are contiguous row ranges).
__global__ __launch_bounds__(256) void k_scan_mean(
    const float* __restrict__ latent,   // [NB][SEQ][DIM] f32
    const int*   __restrict__ mask,     // [NB][SEQ] int32 in {0,1}
    float*       __restrict__ mean)     // [NB][NP][DIM] f32 (workspace)
{
    __shared__ int s_cnt[256];
    __shared__ int s_pos[9];
    const int b   = blockIdx.x;
    const int tid = threadIdx.x;
    const int* mb = mask + (size_t)b * SEQ;

    // each thread loads 16 consecutive mask ints (int4 x4), counts ones
    int4 mv[4];
    const int4* m4 = (const int4*)(mb + tid * 16);
    int cnt = 0;
    #pragma unroll
    for (int i = 0; i < 4; ++i) {
        mv[i] = m4[i];
        cnt += mv[i].x + mv[i].y + mv[i].z + mv[i].w;
    }
    s_cnt[tid] = cnt;
    if (tid < 9) s_pos[tid] = SEQ;   // sentinel: "this one doesn't exist"
    __syncthreads();

    // Hillis-Steele inclusive scan over 256 per-thread counts
    int val = cnt;
    for (int off = 1; off < 256; off <<= 1) {
        int other = (tid >= off) ? s_cnt[tid - off] : 0;
        __syncthreads();
        val += other;
        s_cnt[tid] = val;
        __syncthreads();
    }
    const int excl = val - cnt;      // # ones strictly before my chunk

    // record positions of ones with global rank < 9 (each rank unique -> no race)
    if (excl < 9) {
        int rank = excl;
        const int* me = (const int*)mv;
        #pragma unroll
        for (int i = 0; i < 16; ++i) {
            if (me[i]) {
                if (rank < 9) s_pos[rank] = tid * 16 + i;
                ++rank;
            }
        }
    }
    __syncthreads();

    // bucket p = rows (pos[p-1], min(pos[p], SEQ-1)]  (pos[-1] = -1)
    const float4* lb = (const float4*)(latent + (size_t)b * SEQ * DIM);
    float4*       mo = (float4*)(mean + (size_t)b * NP * DIM);
    for (int p = 0; p < NP; ++p) {
        const int start = (p == 0) ? 0 : s_pos[p - 1] + 1;
        const int endi  = min(s_pos[p], SEQ - 1);
        float4 acc = make_float4(0.f, 0.f, 0.f, 0.f);
        for (int r = start; r <= endi; ++r) {
            float4 v = lb[(size_t)r * (DIM / 4) + tid];
            acc.x += v.x; acc.y += v.y; acc.z += v.z; acc.w += v.w;
        }
        const int count = endi - start + 1;
        const float inv = (count > 0) ? 1.0f / (float)count : 0.0f;
        acc.x *= inv; acc.y *= inv; acc.z *= inv; acc.w *= inv;
        mo[p * (DIM / 4) + tid] = acc;
    }
}

// Kernel 2: out[r][i] = sum_d mean[r][d] * W[i][d] + bias[i]
// M=64 rows (all in As), 64-wide i-tiles, K staged in 64 chunks.
__global__ __launch_bounds__(256) void k_gemm(
    const float* __restrict__ mean,   // [M][DIM]
    const float* __restrict__ Wm,     // [DIM][DIM] row-major
    const float* __restrict__ bias,   // [DIM]
    float*       __restrict__ out)    // [M][DIM]
{
    __shared__ float As[64][65];      // As[r][kk]  (pad 65: conflict-free)
    __shared__ float Bs[64][65];      // Bs[kk][col] = W[i0+col][k0+kk]
    const int i0  = blockIdx.x * 64;
    const int tid = threadIdx.x;
    const int tx  = tid & 15;         // output col group
    const int ty  = tid >> 4;         // output row group
    float acc[4][4] = {};

    for (int k0 = 0; k0 < DIM; k0 += 64) {
        #pragma unroll
        for (int l = 0; l < 4; ++l) {
            const int idx = tid + l * 256;       // float4 index 0..1023
            const int r   = idx >> 4;            // 0..63
            const int c4  = (idx & 15) * 4;      // 0..60
            float4 va = *(const float4*)&mean[(size_t)r * DIM + k0 + c4];
            As[r][c4 + 0] = va.x; As[r][c4 + 1] = va.y;
            As[r][c4 + 2] = va.z; As[r][c4 + 3] = va.w;
            float4 vb = *(const float4*)&Wm[(size_t)(i0 + r) * DIM + k0 + c4];
            Bs[c4 + 0][r] = vb.x; Bs[c4 + 1][r] = vb.y;
            Bs[c4 + 2][r] = vb.z; Bs[c4 + 3][r] = vb.w;
        }
        __syncthreads();
        #pragma unroll
        for (int kk = 0; kk < 64; ++kk) {
            float a[4], w[4];
            #pragma unroll
            for (int i = 0; i < 4; ++i) a[i] = As[ty * 4 + i][kk];
            #pragma unroll
            for (int i = 0; i < 4; ++i) w[i] = Bs[kk][tx * 4 + i];
            #pragma unroll
            for (int ri = 0; ri < 4; ++ri)
                #pragma unroll
                for (int ci = 0; ci < 4; ++ci)
                    acc[ri][ci] += a[ri] * w[ci];
        }
        __syncthreads();
    }

    #pragma unroll
    for (int ri = 0; ri < 4; ++ri) {
        const int r = ty * 4 + ri;
        const int c = i0 + tx * 4;
        float4 o;
        o.x = acc[ri][0] + bias[c + 0];
        o.y = acc[ri][1] + bias[c + 1];
        o.z = acc[ri][2] + bias[c + 2];
        o.w = acc[ri][3] + bias[c + 3];
        *(float4*)&out[(size_t)r * DIM + c] = o;
    }
}

extern "C" void kernel_launch(void* const* d_in, const int* in_sizes, int n_in,
                              void* d_out, int out_size, void* d_ws, size_t ws_size,
                              hipStream_t stream) {
    const float* latent = (const float*)d_in[0];   // (8,4096,1024) f32
    const int*   mask   = (const int*)d_in[1];     // (8,4096,1) int32
    const float* Wm     = (const float*)d_in[2];   // (1024,1024) f32
    const float* bias   = (const float*)d_in[3];   // (1024,) f32
    float* out  = (float*)d_out;                   // (8,8,1024) f32
    float* mean = (float*)d_ws;                    // 64*1024 f32 = 256 KB

    k_scan_mean<<<NB, 256, 0, stream>>>(latent, mask, mean);
    k_gemm<<<DIM / 64, 256, 0, stream>>>(mean, Wm, bias, out);
}

// Round 2
// 20.221 us; speedup vs baseline: 3.0073x; 3.0073x over previous
//
#include <hip/hip_runtime.h>

#define SEQ 4096
#define DIM 1024
#define NB  8
#define NP  8
#define M   64        // NB*NP rows
#define KSPLIT 8      // K-split factor for GEMM
#define KBLK (DIM / KSPLIT)   // 128

// ---------------------------------------------------------------------------
// Kernel 1: grid = NB*NP blocks. Block (b,p): scan batch-b mask for positions
// of the first 9 ones, then compute bucket-p mean (contiguous row range).
// ---------------------------------------------------------------------------
__global__ __launch_bounds__(256) void k_scan_mean(
    const float* __restrict__ latent,   // [NB][SEQ][DIM] f32
    const int*   __restrict__ mask,     // [NB][SEQ] int32 in {0,1}
    float*       __restrict__ mean)     // [NB][NP][DIM] f32 (workspace)
{
    __shared__ int s_cnt[256];
    __shared__ int s_pos[9];
    const int b   = blockIdx.x >> 3;
    const int p   = blockIdx.x & 7;
    const int tid = threadIdx.x;
    const int* mb = mask + (size_t)b * SEQ;

    // each thread loads 16 consecutive mask ints (int4 x4), counts ones
    int4 mv[4];
    const int4* m4 = (const int4*)(mb + tid * 16);
    int cnt = 0;
    #pragma unroll
    for (int i = 0; i < 4; ++i) {
        mv[i] = m4[i];
        cnt += mv[i].x + mv[i].y + mv[i].z + mv[i].w;
    }
    s_cnt[tid] = cnt;
    if (tid < 9) s_pos[tid] = SEQ;   // sentinel: "this one doesn't exist"
    __syncthreads();

    // Hillis-Steele inclusive scan over 256 per-thread counts
    int val = cnt;
    for (int off = 1; off < 256; off <<= 1) {
        int other = (tid >= off) ? s_cnt[tid - off] : 0;
        __syncthreads();
        val += other;
        s_cnt[tid] = val;
        __syncthreads();
    }
    const int excl = val - cnt;      // # ones strictly before my chunk

    // record positions of ones with global rank < 9 (ranks unique -> no race)
    if (excl < 9) {
        int rank = excl;
        const int* me = (const int*)mv;
        #pragma unroll
        for (int i = 0; i < 16; ++i) {
            if (me[i]) {
                if (rank < 9) s_pos[rank] = tid * 16 + i;
                ++rank;
            }
        }
    }
    __syncthreads();

    // bucket p = rows (pos[p-1], min(pos[p], SEQ-1)]   (pos[-1] = -1)
    const int start = (p == 0) ? 0 : s_pos[p - 1] + 1;
    const int endi  = min(s_pos[p], SEQ - 1);
    const float4* lb = (const float4*)(latent + (size_t)b * SEQ * DIM);
    float4 acc = make_float4(0.f, 0.f, 0.f, 0.f);
    for (int r = start; r <= endi; ++r) {
        float4 v = lb[(size_t)r * (DIM / 4) + tid];
        acc.x += v.x; acc.y += v.y; acc.z += v.z; acc.w += v.w;
    }
    const int count = endi - start + 1;
    const float inv = (count > 0) ? 1.0f / (float)count : 0.0f;
    acc.x *= inv; acc.y *= inv; acc.z *= inv; acc.w *= inv;
    ((float4*)(mean + (size_t)(b * NP + p) * DIM))[tid] = acc;
}

// ---------------------------------------------------------------------------
// Kernel 2: partial GEMM.  grid = (16 col-tiles, KSPLIT k-slices).
// Block (ct,ks): partial[ks][0:64][ct*64 : ct*64+64] over K = ks*128..+127.
// ---------------------------------------------------------------------------
__global__ __launch_bounds__(256) void k_gemm_partial(
    const float* __restrict__ mean,     // [M][DIM]
    const float* __restrict__ Wm,       // [DIM][DIM] row-major
    float*       __restrict__ partial)  // [KSPLIT][M][DIM]
{
    __shared__ float As[64][65];      // As[r][kk]
    __shared__ float Bs[64][65];      // Bs[kk][col] = W[i0+col][k0+kk]
    const int i0    = blockIdx.x * 64;
    const int kbase = blockIdx.y * KBLK;
    const int tid   = threadIdx.x;
    const int tx    = tid & 15;       // output col group
    const int ty    = tid >> 4;       // output row group
    float acc[4][4] = {};

    for (int k0 = kbase; k0 < kbase + KBLK; k0 += 64) {
        #pragma unroll
        for (int l = 0; l < 4; ++l) {
            const int idx = tid + l * 256;       // float4 index 0..1023
            const int r   = idx >> 4;            // 0..63
            const int c4  = (idx & 15) * 4;      // 0..60
            float4 va = *(const float4*)&mean[(size_t)r * DIM + k0 + c4];
            As[r][c4 + 0] = va.x; As[r][c4 + 1] = va.y;
            As[r][c4 + 2] = va.z; As[r][c4 + 3] = va.w;
            float4 vb = *(const float4*)&Wm[(size_t)(i0 + r) * DIM + k0 + c4];
            Bs[c4 + 0][r] = vb.x; Bs[c4 + 1][r] = vb.y;
            Bs[c4 + 2][r] = vb.z; Bs[c4 + 3][r] = vb.w;
        }
        __syncthreads();
        #pragma unroll
        for (int kk = 0; kk < 64; ++kk) {
            float a[4], w[4];
            #pragma unroll
            for (int i = 0; i < 4; ++i) a[i] = As[ty * 4 + i][kk];
            #pragma unroll
            for (int i = 0; i < 4; ++i) w[i] = Bs[kk][tx * 4 + i];
            #pragma unroll
            for (int ri = 0; ri < 4; ++ri)
                #pragma unroll
                for (int ci = 0; ci < 4; ++ci)
                    acc[ri][ci] += a[ri] * w[ci];
        }
        __syncthreads();
    }

    float* pbase = partial + (size_t)blockIdx.y * M * DIM;
    #pragma unroll
    for (int ri = 0; ri < 4; ++ri) {
        const int r = ty * 4 + ri;
        const int c = i0 + tx * 4;
        float4 o = make_float4(acc[ri][0], acc[ri][1], acc[ri][2], acc[ri][3]);
        *(float4*)&pbase[(size_t)r * DIM + c] = o;
    }
}

// ---------------------------------------------------------------------------
// Kernel 3: fixed-order reduction over KSPLIT partials + bias (deterministic).
// grid = 64 blocks x 256 threads, one float4 per thread.
// ---------------------------------------------------------------------------
__global__ __launch_bounds__(256) void k_reduce(
    const float* __restrict__ partial,  // [KSPLIT][M][DIM]
    const float* __restrict__ bias,     // [DIM]
    float*       __restrict__ out)      // [M][DIM]
{
    const int idx4 = blockIdx.x * 256 + threadIdx.x;   // 0..16383
    const float4* p4 = (const float4*)partial;
    float4 acc = ((const float4*)bias)[idx4 & (DIM / 4 - 1)];
    #pragma unroll
    for (int ks = 0; ks < KSPLIT; ++ks) {
        float4 v = p4[(size_t)ks * (M * DIM / 4) + idx4];
        acc.x += v.x; acc.y += v.y; acc.z += v.z; acc.w += v.w;
    }
    ((float4*)out)[idx4] = acc;
}

extern "C" void kernel_launch(void* const* d_in, const int* in_sizes, int n_in,
                              void* d_out, int out_size, void* d_ws, size_t ws_size,
                              hipStream_t stream) {
    const float* latent = (const float*)d_in[0];   // (8,4096,1024) f32
    const int*   mask   = (const int*)d_in[1];     // (8,4096,1) int32
    const float* Wm     = (const float*)d_in[2];   // (1024,1024) f32
    const float* bias   = (const float*)d_in[3];   // (1024,) f32
    float* out     = (float*)d_out;                // (8,8,1024) f32
    float* mean    = (float*)d_ws;                 // M*DIM f32       (256 KB)
    float* partial = mean + M * DIM;               // KSPLIT*M*DIM f32 (2 MB)

    k_scan_mean<<<NB * NP, 256, 0, stream>>>(latent, mask, mean);
    k_gemm_partial<<<dim3(DIM / 64, KSPLIT), 256, 0, stream>>>(mean, Wm, partial);
    k_reduce<<<M * DIM / 4 / 256, 256, 0, stream>>>(partial, bias, out);
}